// Round 6
// baseline (617.067 us; speedup 1.0000x reference)
//
#include <hip/hip_runtime.h>

// Problem constants (fixed by setup_inputs)
#define B_ 8
#define T_ 2048
#define C_ 1024
#define H_ 4096
#define E_ 8
#define S_ (2 * T_)          // slots per batch row (K=2)
#define CAP 320              // int(T/E * 1.25)
#define ME 2560              // rows per expert = B_*CAP (10 x 256)
#define NROWS (E_ * ME)      // 20480 bucket rows

typedef __attribute__((ext_vector_type(8))) short short8;
typedef __attribute__((ext_vector_type(4))) float f32x4;

__device__ __forceinline__ unsigned short f2bf(float f) {
  unsigned u = __float_as_uint(f);
  unsigned r = 0x7FFFu + ((u >> 16) & 1u);   // RNE, no NaN in this data
  return (unsigned short)((u + r) >> 16);
}
__device__ __forceinline__ float bf2f(unsigned short u) {
  return __uint_as_float(((unsigned)u) << 16);
}

__device__ __forceinline__ void gload_lds16(const void* g, void* l) {
  __builtin_amdgcn_global_load_lds(
      (const __attribute__((address_space(1))) unsigned int*)g,
      (__attribute__((address_space(3))) unsigned int*)l, 16, 0, 0);
}

// ---------------- weight transpose+convert ----------------
// in: [R][Cc] fp32 (expert blockIdx.z) -> out: [Cc][R] bf16
__global__ void cvt_transpose(const float* __restrict__ in,
                              unsigned short* __restrict__ out, int R, int Cc) {
  __shared__ float t[64][65];
  const int tid = threadIdx.x;
  const long eoff = (long)blockIdx.z * R * Cc;
  const int r0 = blockIdx.x * 64, c0 = blockIdx.y * 64;
#pragma unroll
  for (int it = 0; it < 4; ++it) {
    int r = it * 16 + (tid >> 4);
    int c = (tid & 15) * 4;
    float4 v = *(const float4*)(in + eoff + (long)(r0 + r) * Cc + c0 + c);
    t[r][c] = v.x; t[r][c + 1] = v.y; t[r][c + 2] = v.z; t[r][c + 3] = v.w;
  }
  __syncthreads();
#pragma unroll
  for (int it = 0; it < 4; ++it) {
    int oc = it * 16 + (tid >> 4);   // column index (output row c0+oc)
    int orr = (tid & 15) * 4;        // original rows r0+orr..+3 (output cols)
    union { unsigned short u[4]; unsigned long long ll; } o;
    o.u[0] = f2bf(t[orr + 0][oc]); o.u[1] = f2bf(t[orr + 1][oc]);
    o.u[2] = f2bf(t[orr + 2][oc]); o.u[3] = f2bf(t[orr + 3][oc]);
    *(unsigned long long*)(out + eoff + (long)(c0 + oc) * R + r0 + orr) = o.ll;
  }
}

// ---------------- fused router + x->bf16 convert: one wave per token --------
__global__ void router_cvt(const float* __restrict__ x, const float* __restrict__ Wr,
                           int* __restrict__ es, float* __restrict__ ps,
                           unsigned short* __restrict__ x_bf) {
  const int token = blockIdx.x * 4 + (threadIdx.x >> 6);
  const int lane = threadIdx.x & 63;
  const float* xr = x + (long)token * C_;
  float acc[8] = {0, 0, 0, 0, 0, 0, 0, 0};
#pragma unroll
  for (int j = 0; j < 4; ++j) {
    int c = j * 256 + lane * 4;
    float4 xv = *(const float4*)(xr + c);
    union { unsigned short u[4]; unsigned long long ll; } o;
    o.u[0] = f2bf(xv.x); o.u[1] = f2bf(xv.y); o.u[2] = f2bf(xv.z); o.u[3] = f2bf(xv.w);
    *(unsigned long long*)(x_bf + (long)token * C_ + c) = o.ll;
    const float xe[4] = {xv.x, xv.y, xv.z, xv.w};
#pragma unroll
    for (int i = 0; i < 4; ++i) {
      const float4* wr = (const float4*)(Wr + (long)(c + i) * 8);
      float4 w0 = wr[0], w1 = wr[1];
      float v = xe[i];
      acc[0] += v * w0.x; acc[1] += v * w0.y; acc[2] += v * w0.z; acc[3] += v * w0.w;
      acc[4] += v * w1.x; acc[5] += v * w1.y; acc[6] += v * w1.z; acc[7] += v * w1.w;
    }
  }
#pragma unroll
  for (int off = 32; off >= 1; off >>= 1)
#pragma unroll
    for (int e = 0; e < 8; ++e) acc[e] += __shfl_xor(acc[e], off);
  float mx = acc[0];
#pragma unroll
  for (int e = 1; e < 8; ++e) mx = fmaxf(mx, acc[e]);
  float pr[8], se = 0.f;
#pragma unroll
  for (int e = 0; e < 8; ++e) { pr[e] = expf(acc[e] - mx); se += pr[e]; }
  float inv = 1.f / se;
  // top-2 on probs, jax tie-break: lower index wins on equality (strict >)
  int e0 = 0; float v0 = pr[0];
#pragma unroll
  for (int e = 1; e < 8; ++e) if (pr[e] > v0) { v0 = pr[e]; e0 = e; }
  int e1 = -1; float v1 = -1.f;
#pragma unroll
  for (int e = 0; e < 8; ++e) if (e != e0 && pr[e] > v1) { v1 = pr[e]; e1 = e; }
  if (lane == 0) {
    es[2 * token] = e0;     ps[2 * token] = v0 * inv;
    es[2 * token + 1] = e1; ps[2 * token + 1] = v1 * inv;
  }
}

// ---------------- positions: sequential scan per batch row ----------------
// tsrc[e*ME + b*CAP + pos] = global x row (b*T + t); -1 where bucket empty.
__global__ void positions(const int* __restrict__ es, int* __restrict__ pos,
                          int* __restrict__ tsrc) {
  const int b = blockIdx.x;
  const int lane = threadIdx.x;  // 64 threads
  int cnt[8] = {0, 0, 0, 0, 0, 0, 0, 0};
  unsigned long long below = (1ULL << lane) - 1ULL;
  int e_next = es[(long)b * S_ + lane];
  for (int chunk = 0; chunk < S_ / 64; ++chunk) {
    int e = e_next;
    if (chunk + 1 < S_ / 64) e_next = es[(long)b * S_ + (chunk + 1) * 64 + lane];
    int myPos = 0;
#pragma unroll
    for (int ei = 0; ei < 8; ++ei) {
      unsigned long long m = __ballot(e == ei);
      if (e == ei) myPos = cnt[ei] + __popcll(m & below);
      cnt[ei] += __popcll(m);
    }
    int s = chunk * 64 + lane;
    pos[(long)b * S_ + s] = myPos;
    if (myPos < CAP)
      tsrc[(long)e * ME + b * CAP + myPos] = b * T_ + (s >> 1);
  }
}

// --- 256x256 grouped GEMM, 4-slot ring / 3-slice prefetch lead (T2-T5) -----
// 8 waves (2M x 4N), per-wave 128x64 out. K processed in 32-wide slices;
// Kslice fixed 1024 -> S=32 segments. LDS: ring of 4 slots, each holding one
// (A,B) slice pair (32 KB); 128 KB total.
// Segment t: ds_read slice t from slot t&3 (12x ds_read_b128, swizzled);
// stage slice t+3 into slot (t+3)&3 (4x gload_lds16/wave); 32 MFMA;
// s_waitcnt vmcnt(8) -- drains slice t+1, which was ISSUED 3 SEGMENTS AGO
// (~1000+ cyc lead >= HBM latency; round-5's failure was a 1.5-segment lead);
// raw s_barrier (never __syncthreads: that re-inserts the vmcnt(0) drain).
// Tail peels to vmcnt(4)/vmcnt(0)/none. Write-hazard: slot (t+3)&3 was last
// read in segment t-1, whose end barrier precedes this stage in program order.
// Swizzle (rule #21): in-slice 16B slot = j ^ ((row>>1)&3); gload_lds dest
// linear, source pre-permuted, ds_read applies the same involution (0 bank
// conflicts measured rounds 3-5).
template <bool GATHER, bool RELU>
__global__ __launch_bounds__(512, 2) void moe_gemm256(
    const unsigned short* __restrict__ A, const unsigned short* __restrict__ BT,
    const float* __restrict__ bias, const int* __restrict__ tsrc,
    unsigned short* __restrict__ out01, unsigned short* __restrict__ out23,
    const int Kfull, const int NT, const int KS) {
  constexpr int MT = ME / 256;  // 10
  constexpr int SEG = 32;       // Kslice = 1024 = 32 slices of 32
  __shared__ unsigned short As[4][256 * 32];  // 64 KB
  __shared__ unsigned short Bs[4][256 * 32];  // 64 KB
  const int tid = threadIdx.x, lane = tid & 63, w = tid >> 6;
  const int wr = w >> 2, wc = w & 3;
  const int N = NT * 256;

  // grid: E*KS*NT*MT (mt fastest), XCD-chunked (grid always %8==0)
  const int nwg = E_ * KS * NT * MT;
  const int chunk = nwg >> 3;
  const int swz = (blockIdx.x & 7) * chunk + (blockIdx.x >> 3);
  const int mt = swz % MT;
  int rem = swz / MT;
  const int nt = rem % NT; rem /= NT;
  const int ks = rem % KS;
  const int e = rem / KS;
  const int n0 = nt * 256;
  const long ksoff = (long)ks * 1024;

  // staging sources: issue (matrix, half i) covers rows i*128+w*16+(lane>>2),
  // 16B slot lane&3; source slot pre-swizzled (lane&3)^((lane>>3)&3).
  const int srow = lane >> 2;
  const int psrc = ((lane & 3) ^ ((lane >> 3) & 3)) << 3;  // elems
  const unsigned short* aSrc[2];
  const unsigned short* bSrc[2];
#pragma unroll
  for (int i = 0; i < 2; ++i) {
    int r = i * 128 + w * 16 + srow;
    long rowbase;
    if constexpr (GATHER) {
      int xrow = tsrc[(long)e * ME + mt * 256 + r];
      if (xrow < 0) xrow = 0;  // empty bucket row: garbage, never gathered back
      rowbase = (long)xrow * Kfull;
    } else {
      rowbase = ((long)e * ME + mt * 256 + r) * (long)Kfull;
    }
    aSrc[i] = A + rowbase + ksoff + psrc;
    bSrc[i] = BT + ((long)e * N + n0 + i * 128 + w * 16 + srow) * (long)Kfull +
              ksoff + psrc;
  }

  f32x4 acc[8][4];
#pragma unroll
  for (int m = 0; m < 8; ++m)
#pragma unroll
    for (int n = 0; n < 4; ++n) acc[m][n] = (f32x4){0.f, 0.f, 0.f, 0.f};

  const int l15 = lane & 15, l4 = lane >> 4;
  // ds_read slot perm: row = R0 + l15 (R0%16==0) -> (row>>1)&3 = (l15>>1)&3
  const int rslot = ((l4 ^ ((l15 >> 1) & 3)) << 3);  // elems

  // prologue: stage slices 0,1,2 (12 issues/wave); vmcnt(8) -> slice 0 landed.
#pragma unroll
  for (int s = 0; s < 3; ++s) {
#pragma unroll
    for (int i = 0; i < 2; ++i)
      gload_lds16(aSrc[i] + s * 32, &As[s][(i * 128 + w * 16) * 32]);
#pragma unroll
    for (int i = 0; i < 2; ++i)
      gload_lds16(bSrc[i] + s * 32, &Bs[s][(i * 128 + w * 16) * 32]);
  }
  asm volatile("s_waitcnt vmcnt(8)" ::: "memory");
  __builtin_amdgcn_s_barrier();
  __builtin_amdgcn_sched_barrier(0);

  // segment body: ds_read slice t, optionally stage slice t+3, 32 MFMA.
  auto seg = [&](int t, bool doStage) {
    const int cb = t & 3;
    short8 bf[4], af[8];
#pragma unroll
    for (int n = 0; n < 4; ++n) {
      int rb = wc * 64 + n * 16 + l15;
      bf[n] = *(const short8*)&Bs[cb][rb * 32 + rslot];
    }
#pragma unroll
    for (int m = 0; m < 8; ++m) {
      int r = wr * 128 + m * 16 + l15;
      af[m] = *(const short8*)&As[cb][r * 32 + rslot];
    }
    if (doStage) {
      const int nb = (t + 3) & 3;
      const long koff = (long)(t + 3) * 32;
#pragma unroll
      for (int i = 0; i < 2; ++i)
        gload_lds16(aSrc[i] + koff, &As[nb][(i * 128 + w * 16) * 32]);
#pragma unroll
      for (int i = 0; i < 2; ++i)
        gload_lds16(bSrc[i] + koff, &Bs[nb][(i * 128 + w * 16) * 32]);
    }
    __builtin_amdgcn_s_setprio(1);
#pragma unroll
    for (int m = 0; m < 8; ++m)
#pragma unroll
      for (int n = 0; n < 4; ++n)
        acc[m][n] = __builtin_amdgcn_mfma_f32_16x16x32_bf16(af[m], bf[n],
                                                            acc[m][n], 0, 0, 0);
    __builtin_amdgcn_s_setprio(0);
    __builtin_amdgcn_sched_barrier(0);
  };

  for (int t = 0; t < SEG - 3; ++t) {
    seg(t, true);
    asm volatile("s_waitcnt vmcnt(8)" ::: "memory");  // slice t+1 ready
    __builtin_amdgcn_s_barrier();
    __builtin_amdgcn_sched_barrier(0);
  }
  seg(SEG - 3, false);
  asm volatile("s_waitcnt vmcnt(4)" ::: "memory");    // slice SEG-2 ready
  __builtin_amdgcn_s_barrier();
  __builtin_amdgcn_sched_barrier(0);
  seg(SEG - 2, false);
  asm volatile("s_waitcnt vmcnt(0)" ::: "memory");    // slice SEG-1 ready
  __builtin_amdgcn_s_barrier();
  __builtin_amdgcn_sched_barrier(0);
  seg(SEG - 1, false);

  // epilogue: C/D layout col=lane&15, row=(lane>>4)*4+j  [m89]
  unsigned short* outp = (ks & 2) ? out23 : out01;
  const long rbase = (long)(ks & 1) * NROWS + (long)e * ME + mt * 256;
#pragma unroll
  for (int m = 0; m < 8; ++m) {
#pragma unroll
    for (int n = 0; n < 4; ++n) {
      const int trow = wr * 128 + m * 16 + (l4 << 2);
      const int col = n0 + wc * 64 + n * 16 + l15;
      const float bv = (ks == 0) ? bias[(long)e * N + col] : 0.f;
#pragma unroll
      for (int j = 0; j < 4; ++j) {
        float v = acc[m][n][j] + bv;
        if constexpr (RELU) v = fmaxf(v, 0.f);
        outp[(rbase + trow + j) * (long)N + col] = f2bf(v);
      }
    }
  }
}

// ---------------- combine (y = 4 bf16 split-K partials) ----------------
__global__ void combine(const unsigned short* __restrict__ y01,
                        const unsigned short* __restrict__ y23,
                        const int* __restrict__ es, const float* __restrict__ ps,
                        const int* __restrict__ pos, float* __restrict__ out) {
  const int token = blockIdx.x;  // b*T + t
  const int b = token >> 11;     // T = 2048
  const int s0 = 2 * token, s1 = s0 + 1;
  int e0 = es[s0], e1 = es[s1];
  int q0 = pos[s0], q1 = pos[s1];
  float p0 = ps[s0], p1 = ps[s1];
  const bool k0 = q0 < CAP, k1 = q1 < CAP;
  if (q0 > CAP - 1) q0 = CAP - 1;
  if (q1 > CAP - 1) q1 = CAP - 1;
  const long half = (long)NROWS * C_;
  const long o0 = ((long)e0 * ME + b * CAP + q0) * C_;
  const long o1 = ((long)e1 * ME + b * CAP + q1) * C_;
  const int c = threadIdx.x * 4;  // 256 threads x 4 cols
  float4 a = {0.f, 0.f, 0.f, 0.f};
  union U { unsigned short u[4]; unsigned long long ll; };
  if (k0) {
    U v0_, v1_, v2_, v3_;
    v0_.ll = *(const unsigned long long*)(y01 + o0 + c);
    v1_.ll = *(const unsigned long long*)(y01 + o0 + half + c);
    v2_.ll = *(const unsigned long long*)(y23 + o0 + c);
    v3_.ll = *(const unsigned long long*)(y23 + o0 + half + c);
#pragma unroll
    for (int i = 0; i < 4; ++i) {
      float s = bf2f(v0_.u[i]) + bf2f(v1_.u[i]) + bf2f(v2_.u[i]) + bf2f(v3_.u[i]);
      (&a.x)[i] += p0 * s;
    }
  }
  if (k1) {
    U v0_, v1_, v2_, v3_;
    v0_.ll = *(const unsigned long long*)(y01 + o1 + c);
    v1_.ll = *(const unsigned long long*)(y01 + o1 + half + c);
    v2_.ll = *(const unsigned long long*)(y23 + o1 + c);
    v3_.ll = *(const unsigned long long*)(y23 + o1 + half + c);
#pragma unroll
    for (int i = 0; i < 4; ++i) {
      float s = bf2f(v0_.u[i]) + bf2f(v1_.u[i]) + bf2f(v2_.u[i]) + bf2f(v3_.u[i]);
      (&a.x)[i] += p1 * s;
    }
  }
  *(float4*)(out + (long)token * C_ + c) = a;
}

// ---------------- launch ----------------
extern "C" void kernel_launch(void* const* d_in, const int* in_sizes, int n_in,
                              void* d_out, int out_size, void* d_ws, size_t ws_size,
                              hipStream_t stream) {
  const float* x = (const float*)d_in[0];
  const float* Wr = (const float*)d_in[1];
  const float* W1 = (const float*)d_in[2];
  const float* b1 = (const float*)d_in[3];
  const float* W2 = (const float*)d_in[4];
  const float* b2 = (const float*)d_in[5];
  float* out = (float*)d_out;
  char* ws = (char*)d_ws;
  // workspace layout (~420 MB). After GEMM1, x_bf+W1T are dead -> y partials
  // 2,3 (84 MB) reuse [0, 84 MB) (stream-ordered, safe).
  unsigned short* x_bf = (unsigned short*)(ws + 0L);          // 33,554,432
  unsigned short* W1T = (unsigned short*)(ws + 33554432L);    // 67,108,864  [E][H][C]
  unsigned short* W2T = (unsigned short*)(ws + 100663296L);   // 67,108,864  [E][C][H]
  unsigned short* h = (unsigned short*)(ws + 167772160L);     // 167,772,160 [NROWS][H]
  unsigned short* y01 = (unsigned short*)(ws + 335544320L);   // 83,886,080  ks 0,1
  unsigned short* y23 = (unsigned short*)(ws + 0L);           // 83,886,080  ks 2,3
  int* es = (int*)(ws + 419430400L);                          // 131,072
  float* ps = (float*)(ws + 419561472L);                      // 131,072
  int* pos = (int*)(ws + 419692544L);                         // 131,072
  int* tsrc = (int*)(ws + 419823616L);                        // 81,920

  cvt_transpose<<<dim3(16, 64, 8), 256, 0, stream>>>(W1, W1T, C_, H_);
  cvt_transpose<<<dim3(64, 16, 8), 256, 0, stream>>>(W2, W2T, H_, C_);
  router_cvt<<<4096, 256, 0, stream>>>(x, Wr, es, ps, x_bf);
  hipMemsetAsync(tsrc, 0xFF, NROWS * sizeof(int), stream);
  positions<<<8, 64, 0, stream>>>(es, pos, tsrc);
  // GEMM1: per-expert M=2560 (10 tiles), N=4096 (NT=16), K=1024, KS=1:
  // grid 8*1*16*10 = 1280 = exactly 5 blocks/CU
  moe_gemm256<true, true><<<1280, 512, 0, stream>>>(x_bf, W1T, b1, tsrc, h, h,
                                                    C_, 16, 1);
  // GEMM2: N=1024 (NT=4), K=4096 split-K=4 (Kslice=1024): grid 8*4*4*10 = 1280
  moe_gemm256<false, false><<<1280, 512, 0, stream>>>(h, W2T, b2, nullptr, y01,
                                                      y23, H_, 4, 4);
  combine<<<16384, 256, 0, stream>>>(y01, y23, es, ps, pos, out);
}

// Round 7
// 559.975 us; speedup vs baseline: 1.1020x; 1.1020x over previous
//
#include <hip/hip_runtime.h>

// Problem constants (fixed by setup_inputs)
#define B_ 8
#define T_ 2048
#define C_ 1024
#define H_ 4096
#define E_ 8
#define S_ (2 * T_)          // slots per batch row (K=2)
#define CAP 320              // int(T/E * 1.25)
#define ME 2560              // rows per expert = B_*CAP (20 x 128)
#define NROWS (E_ * ME)      // 20480 bucket rows

typedef __attribute__((ext_vector_type(8))) short short8;
typedef __attribute__((ext_vector_type(4))) float f32x4;

__device__ __forceinline__ unsigned short f2bf(float f) {
  unsigned u = __float_as_uint(f);
  unsigned r = 0x7FFFu + ((u >> 16) & 1u);   // RNE, no NaN in this data
  return (unsigned short)((u + r) >> 16);
}
__device__ __forceinline__ float bf2f(unsigned short u) {
  return __uint_as_float(((unsigned)u) << 16);
}

__device__ __forceinline__ void gload_lds16(const void* g, void* l) {
  __builtin_amdgcn_global_load_lds(
      (const __attribute__((address_space(1))) unsigned int*)g,
      (__attribute__((address_space(3))) unsigned int*)l, 16, 0, 0);
}

// ---------------- weight transpose+convert (W1 and W2 in one launch) -------
// W1: [E][C][H] fp32 -> W1T [E][H][C] bf16 (8192 tiles of 64x64)
// W2: [E][H][C] fp32 -> W2T [E][C][H] bf16 (8192 tiles)
__global__ void cvt_transpose2(const float* __restrict__ W1,
                               const float* __restrict__ W2,
                               unsigned short* __restrict__ W1T,
                               unsigned short* __restrict__ W2T) {
  __shared__ float t[64][65];
  const int tid = threadIdx.x;
  const int bid = blockIdx.x;
  const float* in;
  unsigned short* out;
  int R, Cc, r0, c0;
  long eoff;
  if (bid < 8192) {            // W1: R=1024, Cc=4096; 16 x 64 tiles/expert
    const int tt = bid;
    const int e = tt >> 10;
    const int rt = (tt >> 6) & 15, ct = tt & 63;
    in = W1; out = W1T; R = C_; Cc = H_;
    r0 = rt * 64; c0 = ct * 64;
    eoff = (long)e * C_ * H_;
  } else {                     // W2: R=4096, Cc=1024; 64 x 16 tiles/expert
    const int tt = bid - 8192;
    const int e = tt >> 10;
    const int rt = (tt & 1023) >> 4, ct = tt & 15;
    in = W2; out = W2T; R = H_; Cc = C_;
    r0 = rt * 64; c0 = ct * 64;
    eoff = (long)e * C_ * H_;
  }
#pragma unroll
  for (int it = 0; it < 4; ++it) {
    int r = it * 16 + (tid >> 4);
    int c = (tid & 15) * 4;
    float4 v = *(const float4*)(in + eoff + (long)(r0 + r) * Cc + c0 + c);
    t[r][c] = v.x; t[r][c + 1] = v.y; t[r][c + 2] = v.z; t[r][c + 3] = v.w;
  }
  __syncthreads();
#pragma unroll
  for (int it = 0; it < 4; ++it) {
    int oc = it * 16 + (tid >> 4);   // column index (output row c0+oc)
    int orr = (tid & 15) * 4;        // original rows r0+orr..+3 (output cols)
    union { unsigned short u[4]; unsigned long long ll; } o;
    o.u[0] = f2bf(t[orr + 0][oc]); o.u[1] = f2bf(t[orr + 1][oc]);
    o.u[2] = f2bf(t[orr + 2][oc]); o.u[3] = f2bf(t[orr + 3][oc]);
    *(unsigned long long*)(out + eoff + (long)(c0 + oc) * R + r0 + orr) = o.ll;
  }
}

// ---------------- fused router + x->bf16 convert: one wave per token --------
__global__ void router_cvt(const float* __restrict__ x, const float* __restrict__ Wr,
                           int* __restrict__ es, float* __restrict__ ps,
                           unsigned short* __restrict__ x_bf) {
  const int token = blockIdx.x * 4 + (threadIdx.x >> 6);
  const int lane = threadIdx.x & 63;
  const float* xr = x + (long)token * C_;
  float acc[8] = {0, 0, 0, 0, 0, 0, 0, 0};
#pragma unroll
  for (int j = 0; j < 4; ++j) {
    int c = j * 256 + lane * 4;
    float4 xv = *(const float4*)(xr + c);
    union { unsigned short u[4]; unsigned long long ll; } o;
    o.u[0] = f2bf(xv.x); o.u[1] = f2bf(xv.y); o.u[2] = f2bf(xv.z); o.u[3] = f2bf(xv.w);
    *(unsigned long long*)(x_bf + (long)token * C_ + c) = o.ll;
    const float xe[4] = {xv.x, xv.y, xv.z, xv.w};
#pragma unroll
    for (int i = 0; i < 4; ++i) {
      const float4* wr = (const float4*)(Wr + (long)(c + i) * 8);
      float4 w0 = wr[0], w1 = wr[1];
      float v = xe[i];
      acc[0] += v * w0.x; acc[1] += v * w0.y; acc[2] += v * w0.z; acc[3] += v * w0.w;
      acc[4] += v * w1.x; acc[5] += v * w1.y; acc[6] += v * w1.z; acc[7] += v * w1.w;
    }
  }
#pragma unroll
  for (int off = 32; off >= 1; off >>= 1)
#pragma unroll
    for (int e = 0; e < 8; ++e) acc[e] += __shfl_xor(acc[e], off);
  float mx = acc[0];
#pragma unroll
  for (int e = 1; e < 8; ++e) mx = fmaxf(mx, acc[e]);
  float pr[8], se = 0.f;
#pragma unroll
  for (int e = 0; e < 8; ++e) { pr[e] = expf(acc[e] - mx); se += pr[e]; }
  float inv = 1.f / se;
  // top-2 on probs, jax tie-break: lower index wins on equality (strict >)
  int e0 = 0; float v0 = pr[0];
#pragma unroll
  for (int e = 1; e < 8; ++e) if (pr[e] > v0) { v0 = pr[e]; e0 = e; }
  int e1 = -1; float v1 = -1.f;
#pragma unroll
  for (int e = 0; e < 8; ++e) if (e != e0 && pr[e] > v1) { v1 = pr[e]; e1 = e; }
  if (lane == 0) {
    es[2 * token] = e0;     ps[2 * token] = v0 * inv;
    es[2 * token + 1] = e1; ps[2 * token + 1] = v1 * inv;
  }
}

// ---------------- positions: sequential scan per batch row ----------------
// tsrc[e*ME + b*CAP + pos] = global x row (b*T + t); -1 where bucket empty.
// Tail-fills -1 itself (replaces the separate memset dispatch).
__global__ void positions(const int* __restrict__ es, int* __restrict__ pos,
                          int* __restrict__ tsrc) {
  const int b = blockIdx.x;
  const int lane = threadIdx.x;  // 64 threads
  int cnt[8] = {0, 0, 0, 0, 0, 0, 0, 0};
  unsigned long long below = (1ULL << lane) - 1ULL;
  int e_next = es[(long)b * S_ + lane];
  for (int chunk = 0; chunk < S_ / 64; ++chunk) {
    int e = e_next;
    if (chunk + 1 < S_ / 64) e_next = es[(long)b * S_ + (chunk + 1) * 64 + lane];
    int myPos = 0;
#pragma unroll
    for (int ei = 0; ei < 8; ++ei) {
      unsigned long long m = __ballot(e == ei);
      if (e == ei) myPos = cnt[ei] + __popcll(m & below);
      cnt[ei] += __popcll(m);
    }
    int s = chunk * 64 + lane;
    pos[(long)b * S_ + s] = myPos;
    if (myPos < CAP)
      tsrc[(long)e * ME + b * CAP + myPos] = b * T_ + (s >> 1);
  }
  // tail fill: slots beyond the bucket's fill get -1 (cnt is wave-uniform)
#pragma unroll
  for (int ei = 0; ei < 8; ++ei)
    for (int p = cnt[ei] + lane; p < CAP; p += 64)
      tsrc[(long)ei * ME + b * CAP + p] = -1;
}

// ---------------- grouped MFMA GEMM, m97 structure (128x128 tile) ----------
// Verified-best structure (round 3: 826 TF eff, MfmaUtil 35.7%, 0 conflicts).
// Per-expert M space = ME (2560) contiguous rows. 1D grid, XCD-chunked so each
// XCD owns one expert; mt fastest -> B-panel L2 reuse x20.
// A (bf16): GATHER ? x_bf [B*T][Kdim] gathered via tsrc : h [NROWS][Kdim]
// BT (bf16): [E][N][Kdim] (pre-transposed, K-contiguous)
// out (bf16): RELU ? relu(acc+bias) : acc+bias
// __launch_bounds__(256,3): >=3 waves/SIMD (round-2 PMC showed 2 waves/SIMD
// was the limiter; this lifted MfmaUtil 26.6 -> 35.7).
template <bool GATHER, bool RELU>
__global__ __launch_bounds__(256, 3) void moe_gemm(
    const unsigned short* __restrict__ A, const unsigned short* __restrict__ BT,
    const float* __restrict__ bias, const int* __restrict__ tsrc,
    unsigned short* __restrict__ outp, const int Kdim, const int N, const int NT) {
  constexpr int BM = 128, BN = 128, BK = 64;
  constexpr int MT = ME / BM;  // 20
  __shared__ unsigned short As[BM * BK];  // 16 KB, XOR-swizzled 16B slots
  __shared__ unsigned short Bs[BN * BK];  // 16 KB
  const int tid = threadIdx.x, lane = tid & 63, w = tid >> 6;

  // XCD-aware swizzle: grid = E_*NT*MT, always divisible by 8.
  const int nwg = E_ * NT * MT;
  const int chunk = nwg >> 3;
  const int swz = (blockIdx.x & 7) * chunk + (blockIdx.x >> 3);
  const int e = swz / (NT * MT);
  const int rem = swz % (NT * MT);
  const int nt = rem / MT, mt = rem % MT;
  const int n0 = nt * BN;

  // staging: wave w covers A rows [w*32,w*32+32) in 4 issues of 8 rows; same B.
  // LDS linear dest + pre-swizzled global source slot (j ^ (row&7)) so the
  // swizzled ds_read below is the matching involution (guide rule #21).
  const unsigned short* aPtr[4];
#pragma unroll
  for (int i = 0; i < 4; ++i) {
    int ra = w * 32 + i * 8 + (lane >> 3);
    int j = lane & 7;
    long rowbase;
    if constexpr (GATHER) {
      int xrow = tsrc[(long)e * ME + mt * BM + ra];
      if (xrow < 0) xrow = 0;  // empty bucket row: garbage, never gathered back
      rowbase = (long)xrow * Kdim;
    } else {
      rowbase = ((long)e * ME + mt * BM + ra) * (long)Kdim;
    }
    aPtr[i] = A + rowbase + ((j ^ (ra & 7)) << 3);
  }
  const unsigned short* bPtr[4];
#pragma unroll
  for (int i = 0; i < 4; ++i) {
    int rb = w * 32 + i * 8 + (lane >> 3);
    int j = lane & 7;
    bPtr[i] = BT + ((long)e * N + n0 + rb) * (long)Kdim + ((j ^ (rb & 7)) << 3);
  }

  const int wm = w >> 1, wn = w & 1;   // 2x2 waves, each 64x64 output
  f32x4 acc[4][4];
#pragma unroll
  for (int m = 0; m < 4; ++m)
#pragma unroll
    for (int n = 0; n < 4; ++n) acc[m][n] = (f32x4){0.f, 0.f, 0.f, 0.f};

  int arow[4], brow[4];
#pragma unroll
  for (int i = 0; i < 4; ++i) {
    arow[i] = wm * 64 + i * 16 + (lane & 15);
    brow[i] = wn * 64 + i * 16 + (lane & 15);
  }
  const int jjb = lane >> 4;

  for (int kt = 0; kt < Kdim / BK; ++kt) {
#pragma unroll
    for (int i = 0; i < 4; ++i)
      gload_lds16(aPtr[i], &As[(w * 32 + i * 8) * BK]);
#pragma unroll
    for (int i = 0; i < 4; ++i)
      gload_lds16(bPtr[i], &Bs[(w * 32 + i * 8) * BK]);
#pragma unroll
    for (int i = 0; i < 4; ++i) { aPtr[i] += BK; bPtr[i] += BK; }
    __syncthreads();
#pragma unroll
    for (int s = 0; s < 2; ++s) {
      short8 af[4], bf[4];
#pragma unroll
      for (int m = 0; m < 4; ++m) {
        int slot = (s * 4 + jjb) ^ (arow[m] & 7);
        af[m] = *(const short8*)&As[arow[m] * BK + slot * 8];
      }
#pragma unroll
      for (int n = 0; n < 4; ++n) {
        int slot = (s * 4 + jjb) ^ (brow[n] & 7);
        bf[n] = *(const short8*)&Bs[brow[n] * BK + slot * 8];
      }
#pragma unroll
      for (int m = 0; m < 4; ++m)
#pragma unroll
        for (int n = 0; n < 4; ++n)
          acc[m][n] = __builtin_amdgcn_mfma_f32_16x16x32_bf16(af[m], bf[n],
                                                              acc[m][n], 0, 0, 0);
    }
    __syncthreads();
  }

  // epilogue: C/D layout col=lane&15, row=(lane>>4)*4+j  [m89]
  const long rbase = (long)e * ME + mt * BM;
#pragma unroll
  for (int m = 0; m < 4; ++m) {
#pragma unroll
    for (int n = 0; n < 4; ++n) {
      const int trow = wm * 64 + m * 16 + ((lane >> 4) << 2);
      const int col = n0 + wn * 64 + n * 16 + (lane & 15);
      const float bv = bias[(long)e * N + col];
#pragma unroll
      for (int j = 0; j < 4; ++j) {
        float v = acc[m][n][j] + bv;
        if constexpr (RELU) v = fmaxf(v, 0.f);
        outp[(rbase + trow + j) * N + col] = f2bf(v);
      }
    }
  }
}

// ---------------- combine (y in bf16) ----------------
__global__ void combine(const unsigned short* __restrict__ y,
                        const int* __restrict__ es, const float* __restrict__ ps,
                        const int* __restrict__ pos, float* __restrict__ out) {
  const int token = blockIdx.x;  // b*T + t
  const int b = token >> 11;     // T = 2048
  const int s0 = 2 * token, s1 = s0 + 1;
  int e0 = es[s0], e1 = es[s1];
  int q0 = pos[s0], q1 = pos[s1];
  float p0 = ps[s0], p1 = ps[s1];
  const bool k0 = q0 < CAP, k1 = q1 < CAP;
  if (q0 > CAP - 1) q0 = CAP - 1;
  if (q1 > CAP - 1) q1 = CAP - 1;
  const unsigned short* r0 = y + ((long)e0 * ME + b * CAP + q0) * C_;
  const unsigned short* r1 = y + ((long)e1 * ME + b * CAP + q1) * C_;
  const int c = threadIdx.x * 4;  // 256 threads x 4 cols
  float4 a = {0.f, 0.f, 0.f, 0.f};
  if (k0) {
    union { unsigned short u[4]; unsigned long long ll; } v;
    v.ll = *(const unsigned long long*)(r0 + c);
    a.x += p0 * bf2f(v.u[0]); a.y += p0 * bf2f(v.u[1]);
    a.z += p0 * bf2f(v.u[2]); a.w += p0 * bf2f(v.u[3]);
  }
  if (k1) {
    union { unsigned short u[4]; unsigned long long ll; } v;
    v.ll = *(const unsigned long long*)(r1 + c);
    a.x += p1 * bf2f(v.u[0]); a.y += p1 * bf2f(v.u[1]);
    a.z += p1 * bf2f(v.u[2]); a.w += p1 * bf2f(v.u[3]);
  }
  *(float4*)(out + (long)token * C_ + c) = a;
}

// ---------------- launch ----------------
extern "C" void kernel_launch(void* const* d_in, const int* in_sizes, int n_in,
                              void* d_out, int out_size, void* d_ws, size_t ws_size,
                              hipStream_t stream) {
  const float* x = (const float*)d_in[0];
  const float* Wr = (const float*)d_in[1];
  const float* W1 = (const float*)d_in[2];
  const float* b1 = (const float*)d_in[3];
  const float* W2 = (const float*)d_in[4];
  const float* b2 = (const float*)d_in[5];
  float* out = (float*)d_out;
  char* ws = (char*)d_ws;
  // workspace layout (~378 MB)
  unsigned short* x_bf = (unsigned short*)(ws + 0L);          // 33,554,432
  unsigned short* W1T = (unsigned short*)(ws + 33554432L);    // 67,108,864  [E][H][C]
  unsigned short* W2T = (unsigned short*)(ws + 100663296L);   // 67,108,864  [E][C][H]
  unsigned short* h = (unsigned short*)(ws + 167772160L);     // 167,772,160 [NROWS][H]
  unsigned short* y = (unsigned short*)(ws + 335544320L);     // 41,943,040  [NROWS][C] bf16
  int* es = (int*)(ws + 377487360L);                          // 131,072
  float* ps = (float*)(ws + 377618432L);                      // 131,072
  int* pos = (int*)(ws + 377749504L);                         // 131,072
  int* tsrc = (int*)(ws + 377880576L);                        // 81,920

  cvt_transpose2<<<16384, 256, 0, stream>>>(W1, W2, W1T, W2T);
  router_cvt<<<4096, 256, 0, stream>>>(x, Wr, es, ps, x_bf);
  positions<<<8, 64, 0, stream>>>(es, pos, tsrc);
  // GEMM1: per-expert M=2560, N=4096 (NT=32): grid 8*32*20 = 5120
  moe_gemm<true, true><<<5120, 256, 0, stream>>>(x_bf, W1T, b1, tsrc, h, C_, H_, 32);
  // GEMM2: N=1024 (NT=8): grid 8*8*20 = 1280
  moe_gemm<false, false><<<1280, 256, 0, stream>>>(h, W2T, b2, nullptr, y, H_, C_, 8);
  combine<<<16384, 256, 0, stream>>>(y, es, ps, pos, out);
}